// Round 7
// baseline (1188.634 us; speedup 1.0000x reference)
//
#include <hip/hip_runtime.h>

// QuantizedLinear via int8 MFMA. 256x128-tile GEMM, 1024 threads (16 waves,
// 4/SIMD), triple-buffered LDS, counted vmcnt (never 0 in loop).
// out[M,N] = x[M,K] @ W[N,K]^T + bias; W int4 exact in i8, x per-row i8.
// BK=128 = one scale group; ci chains i32 over the group (exact), one f32
// drain per tile with group scale.
//
// R6 post-mortem: 191 us, MfmaUtil 32 / VALUBusy 44, no spill (VGPR 60 -
// MFMA C/D sits in the accumulator half of the unified file; the 128-arch-reg
// cap only constrains f32/address regs). Remaining cost: LDS reads (192 KB
// /tile/CU) + VALU (drain 512 cyc + per-iter %3 slot math + address
// recompute). R7: unroll-by-3 (compile-time slots, strength-reduced
// addressing) + scale queue prefetched 2 tiles ahead (no mid-body FIFO wait;
// single vmcnt(5) per body).

typedef int i32x4 __attribute__((ext_vector_type(4)));

#define GAS __attribute__((address_space(1)))
#define LAS __attribute__((address_space(3)))

static constexpr int M_DIM = 8192;
static constexpr int N_DIM = 4096;
static constexpr int K_DIM = 4096;

// ---------------- x fp32 -> i8 per-row (one block per row of 4096) ----------------
__global__ __launch_bounds__(256) void quant_x(const float* __restrict__ x,
                                               signed char* __restrict__ xq,
                                               float* __restrict__ sx) {
    const int row = blockIdx.x;
    const int tid = threadIdx.x;
    const float* xr = x + (size_t)row * K_DIM;
    float4 v[4];
#pragma unroll
    for (int i = 0; i < 4; ++i) v[i] = *(const float4*)(xr + i * 1024 + tid * 4);
    float m = 0.f;
#pragma unroll
    for (int i = 0; i < 4; ++i)
        m = fmaxf(m, fmaxf(fmaxf(fabsf(v[i].x), fabsf(v[i].y)),
                           fmaxf(fabsf(v[i].z), fabsf(v[i].w))));
#pragma unroll
    for (int off = 32; off >= 1; off >>= 1) m = fmaxf(m, __shfl_xor(m, off, 64));
    __shared__ float wm[4];
    if ((tid & 63) == 0) wm[tid >> 6] = m;
    __syncthreads();
    m = fmaxf(fmaxf(wm[0], wm[1]), fmaxf(wm[2], wm[3]));
    const float inv = 127.f / m;
    if (tid == 0) sx[row] = m / 127.f;
#pragma unroll
    for (int i = 0; i < 4; ++i) {
        int b0 = (int)rintf(v[i].x * inv) & 255;
        int b1 = (int)rintf(v[i].y * inv) & 255;
        int b2 = (int)rintf(v[i].z * inv) & 255;
        int b3 = (int)rintf(v[i].w * inv) & 255;
        *(int*)(xq + (size_t)row * K_DIM + i * 1024 + tid * 4) =
            b0 | (b1 << 8) | (b2 << 16) | (b3 << 24);
    }
}

// ---------------- packed int4 -> raw i8 (values q-8 in [-8,7], NO scale) ----------------
__global__ __launch_bounds__(256) void unpack_w(const int* __restrict__ wp,
                                                signed char* __restrict__ wq) {
    const int t = blockIdx.x * 256 + threadIdx.x;   // 4 packed words -> 8 bytes out
    int4 p = *(const int4*)(wp + (size_t)t * 4);
    int pv[4] = {p.x, p.y, p.z, p.w};
    int w01 = (((pv[0] & 15) - 8) & 255) | (((((pv[0] >> 4) & 15) - 8) & 255) << 8) |
              ((((pv[1] & 15) - 8) & 255) << 16) | (((((pv[1] >> 4) & 15) - 8) & 255) << 24);
    int w23 = (((pv[2] & 15) - 8) & 255) | (((((pv[2] >> 4) & 15) - 8) & 255) << 8) |
              ((((pv[3] & 15) - 8) & 255) << 16) | (((((pv[3] >> 4) & 15) - 8) & 255) << 24);
    *(int2*)(wq + (size_t)t * 8) = make_int2(w01, w23);
}

// ---------------- scales [N][32] -> scalesT [32][N] (coalesced gemm reads) ----------------
__global__ __launch_bounds__(256) void transp_scales(const float* __restrict__ s,
                                                     float* __restrict__ st) {
    const int t = blockIdx.x * 256 + threadIdx.x;   // over 4096*32
    st[(size_t)(t & 31) * N_DIM + (t >> 5)] = s[t];
}

// ---------------- i8 GEMM, B^T, 256x128 tile, BK=128, 3-buffer pipeline ----------------
// 1024 thr = 16 waves (4M x 4N); per-wave output 64x32 = 4x2 frags of 16x16.
// LDS 144 KiB: 3 slots of { A 256x128B (32 KB) | B 128x128B (16 KB) }.
// Row = 128 B = 8 chunks of 16 B; chunk c stored at slot c ^ (row&7) (0-conflict).
// Staging: 3 gload_lds/thread/tile (A 2, B 1), linear dest.
//
// Pipeline (2-tile prefetch, unroll-by-3 for compile-time slots):
//   Per-body vmem issues: STAGE(t+2)[3] + sj(t+2)[2].
//   sj queue: sjc = sj(t) [issued body t-2], sjn = sj(t+1) [issued body t-1].
//   Ledger at VMW(5), body t: outstanding <= {stage(t+1)[3], sj(t+1)[2],
//   stage(t+2)[3], sj(t+2)[2]}; keep newest 5 = this body's issues ->
//   retires stage(t+1)+sj(t+1). So after BAR(t): tile t+1 fully in LDS for
//   ALL waves (each wave waited its own DMA before the barrier - the sound
//   cross-wave publication protocol). Tile t's data was published at
//   BAR(t-1) by the same argument. Never vmcnt(0) in loop.
//   Slot overwrite: stage at body t targets slot (t+2)%3 = slot of tile t-1,
//   last read at body t-1 before BAR(t-1); DMA issued after this wave crossed
//   BAR(t-1) -> no race.

#define STAGE(SLOT, TAU) do { \
  _Pragma("unroll") \
  for (int i_ = 0; i_ < 2; ++i_) { \
    const int ch_ = i_ * 1024 + tid; \
    const int row_ = ch_ >> 3; \
    const int c_ = (ch_ & 7) ^ (row_ & 7); \
    const signed char* sA_ = Aq + (size_t)(m0 + row_) * K_DIM \
                                + (size_t)(TAU) * 128 + c_ * 16; \
    __builtin_amdgcn_global_load_lds((const GAS void*)sA_, \
        (LAS void*)(lds + (SLOT) * 49152 + ch_ * 16), 16, 0, 0); \
  } \
  { \
    const int row_ = tid >> 3; \
    const int c_ = (tid & 7) ^ (row_ & 7); \
    const signed char* sB_ = Bq + (size_t)(n0 + row_) * K_DIM \
                                + (size_t)(TAU) * 128 + c_ * 16; \
    __builtin_amdgcn_global_load_lds((const GAS void*)sB_, \
        (LAS void*)(lds + (SLOT) * 49152 + 32768 + tid * 16), 16, 0, 0); \
  } \
} while (0)

#define VMW(N) asm volatile("s_waitcnt vmcnt(" #N ")" ::: "memory")
#define BAR()  do { __builtin_amdgcn_s_barrier(); asm volatile("" ::: "memory"); } while (0)

// One tile body. S = slot of tile T (compile-time), SS = slot staged (t+2).
#define BODY(T, S, SS) do { \
    STAGE(SS, ((T) + 2) & 31); \
    const float sn0_ = scalesT[(size_t)(((T) + 2) & 31) * N_DIM + sjoff]; \
    const float sn1_ = scalesT[(size_t)(((T) + 2) & 31) * N_DIM + sjoff + 16]; \
    const signed char* abase_ = lds + (S) * 49152; \
    const signed char* bbase_ = abase_ + 32768; \
    i32x4 ci[4][2]; \
    _Pragma("unroll") \
    for (int ks = 0; ks < 2; ++ks) { \
        i32x4 bF[2], aF[4]; \
        _Pragma("unroll") \
        for (int nj = 0; nj < 2; ++nj) { \
            const int rb = wc * 32 + nj * 16 + lr; \
            bF[nj] = *(const i32x4*)(bbase_ + rb * 128 + \
                                     ((((ks << 2) | quad) ^ (rb & 7)) << 4)); \
        } \
        _Pragma("unroll") \
        for (int mi = 0; mi < 4; ++mi) { \
            const int ra = wr * 64 + mi * 16 + lr; \
            aF[mi] = *(const i32x4*)(abase_ + ra * 128 + \
                                     ((((ks << 2) | quad) ^ (ra & 7)) << 4)); \
        } \
        __builtin_amdgcn_s_setprio(1); \
        _Pragma("unroll") \
        for (int mi = 0; mi < 4; ++mi) \
            _Pragma("unroll") \
            for (int nj = 0; nj < 2; ++nj) \
                ci[mi][nj] = __builtin_amdgcn_mfma_i32_16x16x64_i8( \
                    aF[mi], bF[nj], ks ? ci[mi][nj] : izero, 0, 0, 0); \
        __builtin_amdgcn_s_setprio(0); \
    } \
    _Pragma("unroll") \
    for (int mi = 0; mi < 4; ++mi) \
        _Pragma("unroll") \
        for (int r = 0; r < 4; ++r) { \
            accf[mi][0][r] += sjc0 * (float)ci[mi][0][r]; \
            accf[mi][1][r] += sjc1 * (float)ci[mi][1][r]; \
        } \
    sjc0 = sjn0; sjc1 = sjn1; sjn0 = sn0_; sjn1 = sn1_; \
    VMW(5); BAR(); \
} while (0)

__global__ __launch_bounds__(1024, 4)
void gemm_i8(const signed char* __restrict__ Aq,
             const signed char* __restrict__ Bq,
             const float* __restrict__ scalesT,
             const float* __restrict__ sx,
             const float* __restrict__ bias,
             float* __restrict__ C) {
    __shared__ signed char lds[147456];   // 3 x 48 KB

    const int tid  = threadIdx.x;          // 0..1023
    const int l    = tid & 63;
    const int wv   = tid >> 6;             // 0..15
    const int wr   = wv >> 2;              // 0..3  (M quarter: 64 rows)
    const int wc   = wv & 3;               // 0..3  (N quarter: 32 cols)
    const int lr   = l & 15;
    const int quad = l >> 4;

    // XCD-aware swizzle: 1024 wgs = 8 XCDs x 128; per-XCD 8x16 tile rect (bijective).
    const int bid = blockIdx.x;
    const int xcd = bid & 7, kk = bid >> 3;          // kk in [0,128)
    const int by = (xcd >> 1) * 8 + (kk & 7);        // m-tile 0..31 (256-row tiles)
    const int bx = (xcd & 1) * 16 + (kk >> 3);       // n-tile 0..31 (128-col tiles)
    const int m0 = by * 256, n0 = bx * 128;

    const int sjoff = n0 + wc * 32 + lr;

    float accf[4][2][4];
#pragma unroll
    for (int i = 0; i < 4; ++i)
#pragma unroll
        for (int j = 0; j < 2; ++j)
#pragma unroll
            for (int r = 0; r < 4; ++r) accf[i][j][r] = 0.f;

    const i32x4 izero = {0, 0, 0, 0};

    // Prologue: stage tiles 0,1 -> slots 0,1; scale queue for tiles 0,1.
    // VMW(5): outstanding = stage0[3], sj0[2], stage1[3], sj1[2] -> keep
    // newest 5 (stage1+sj1), retire stage0+sj0 -> tile 0 published at BAR.
    STAGE(0, 0);
    float sjc0 = scalesT[(size_t)0 * N_DIM + sjoff];
    float sjc1 = scalesT[(size_t)0 * N_DIM + sjoff + 16];
    STAGE(1, 1);
    float sjn0 = scalesT[(size_t)1 * N_DIM + sjoff];
    float sjn1 = scalesT[(size_t)1 * N_DIM + sjoff + 16];
    VMW(5);
    BAR();

#pragma unroll 1
    for (int i = 0; i < 10; ++i) {
        const int t = i * 3;
        BODY(t + 0, 0, 2);
        BODY(t + 1, 1, 0);
        BODY(t + 2, 2, 1);
    }
    BODY(30, 0, 2);   // stages tau (32&31)=0 into dead slot 2 (ledger-preserving)
    BODY(31, 1, 0);   // stages tau 1 into dead slot 0

    // Drain wrap-staged DMA before the block exits.
    asm volatile("s_waitcnt vmcnt(0)" ::: "memory");

    // Epilogue: C/D layout col=lane&15, row=quad*4+reg (verified, dtype-independent)
    float sxr[4][4];
#pragma unroll
    for (int i = 0; i < 4; ++i)
#pragma unroll
        for (int r = 0; r < 4; ++r)
            sxr[i][r] = sx[m0 + wr * 64 + i * 16 + quad * 4 + r];
#pragma unroll
    for (int j = 0; j < 2; ++j) {
        const int gn = n0 + wc * 32 + j * 16 + lr;
        const float bv = bias[gn];
#pragma unroll
        for (int i = 0; i < 4; ++i) {
            const size_t gm = (size_t)m0 + wr * 64 + i * 16 + quad * 4;
#pragma unroll
            for (int r = 0; r < 4; ++r)
                C[(gm + r) * N_DIM + gn] = accf[i][j][r] * sxr[i][r] + bv;
        }
    }
}

extern "C" void kernel_launch(void* const* d_in, const int* in_sizes, int n_in,
                              void* d_out, int out_size, void* d_ws, size_t ws_size,
                              hipStream_t stream) {
    const float* x      = (const float*)d_in[0];   // [4,2048,4096] fp32
    const int*   wp     = (const int*)d_in[1];     // [4096,2048] int32 (uint8 semantics)
    const float* scales = (const float*)d_in[2];   // [4096,32]
    const float* bias   = (const float*)d_in[4];   // [4096]
    float* out = (float*)d_out;

    signed char* Xq = (signed char*)d_ws;                                   // 32 MB
    signed char* Wq = (signed char*)d_ws + (size_t)M_DIM * K_DIM;           // +16 MB
    float* sx  = (float*)((char*)d_ws + (size_t)M_DIM * K_DIM + (size_t)N_DIM * K_DIM);          // +32 KB
    float* scT = (float*)((char*)d_ws + (size_t)M_DIM * K_DIM + (size_t)N_DIM * K_DIM + 32768);  // +512 KB

    quant_x<<<M_DIM, 256, 0, stream>>>(x, Xq, sx);
    unpack_w<<<(N_DIM * (K_DIM / 2) / 4) / 256, 256, 0, stream>>>(wp, Wq);
    transp_scales<<<(N_DIM * 32) / 256, 256, 0, stream>>>(scales, scT);
    gemm_i8<<<dim3(1024), 1024, 0, stream>>>(Xq, Wq, scT, sx, bias, out);
}